// Round 11
// baseline (1908.361 us; speedup 1.0000x reference)
//
#include <hip/hip_runtime.h>
#include <hip/hip_bf16.h>
#include <math.h>
#include <stdint.h>

// Problem constants
#define T_TOK 4096
#define H_DIM 2880
#define E_NUM 16
#define ALPHA 1.702f
#define EPS_RMS 1e-5f

// GEMM: BM=192, BN=192 eff, BK=32; 512 threads = 8 waves (4m x 2n), 48x96/wave.
// A: 3-buf LDS depth-2 via global_load_lds (register-free).
// B: 3-buf LDS, TWO register sets (bvA/bvB, 16 VGPR each) -> pack has a FULL
//    step of latency cover (load at end of step kt-1, pack at end of step kt).
// A and B rotate buffers mod 3 together. Barrier = lgkmcnt(0)+s_barrier only;
// vmcnt(0) only in the 2-step tail.
#define PADM 192
#define BK 32
#define NK (H_DIM / BK)       // 90
#define MAX_RT 104
#define NCT1 30
#define NCT2 15
#define G1 (MAX_RT * NCT1)    // 3120 (div 8)
#define G2 (MAX_RT * NCT2)    // 1560 (div 8)
#define ABUF 12288            // 192 rows x 64 B (x3)
#define BBUF 12288            // 192 rows x 64 B (x3)
#define BOFF 36864            // B region base; total LDS 72 KB

typedef __attribute__((ext_vector_type(8))) short short8;
typedef __attribute__((ext_vector_type(4))) float f32x4;

__device__ __forceinline__ unsigned short f2bf(float f) {
  unsigned u = __float_as_uint(f);
  return (unsigned short)((u + 0x7fffu + ((u >> 16) & 1u)) >> 16);
}
__device__ __forceinline__ unsigned cpk(float a, float b) {
  unsigned r;
  asm("v_cvt_pk_bf16_f32 %0, %1, %2" : "=v"(r) : "v"(a), "v"(b));
  return r;
}
__device__ __forceinline__ void gl_lds16(const void* g, unsigned char* lds_dst) {
  __builtin_amdgcn_global_load_lds(
      (const __attribute__((address_space(1))) void*)g,
      (__attribute__((address_space(3))) void*)lds_dst, 16, 0, 0);
}
#define ENDSTEP() do {                                           \
    asm volatile("s_waitcnt lgkmcnt(0)" ::: "memory");           \
    __builtin_amdgcn_s_barrier();                                \
    __builtin_amdgcn_sched_barrier(0);                           \
  } while (0)

// ---------------- K1: rmsnorm + fp32 gate + top4 ----------------
__global__ __launch_bounds__(256) void k_norm_gate(
    const float* __restrict__ x, const float* __restrict__ norm_w,
    const float* __restrict__ gate_w, const float* __restrict__ gate_b,
    unsigned short* __restrict__ t_out,
    int* __restrict__ topk_id, float* __restrict__ topk_w,
    int* __restrict__ counts)
{
  int t = blockIdx.x, tid = threadIdx.x;
  const float4* xr = (const float4*)(x + (size_t)t * H_DIM);
  float4 xa[3];
  float ss = 0.f;
  int j = 0;
  for (int i = tid; i < 720; i += 256, j++) {
    float4 v = xr[i]; xa[j] = v;
    ss += v.x * v.x + v.y * v.y + v.z * v.z + v.w * v.w;
  }
#pragma unroll
  for (int o = 1; o < 64; o <<= 1) ss += __shfl_xor(ss, o, 64);
  __shared__ float red[4];
  if ((tid & 63) == 0) red[tid >> 6] = ss;
  __syncthreads();
  float rs = rsqrtf((red[0] + red[1] + red[2] + red[3]) * (1.f / H_DIM) + EPS_RMS);

  float part[16];
#pragma unroll
  for (int q = 0; q < 16; q++) part[q] = 0.f;
  j = 0;
  for (int i = tid; i < 720; i += 256, j++) {
    float4 v = xa[j];
    float4 w = ((const float4*)norm_w)[i];
    float t0 = v.x * rs * w.x, t1 = v.y * rs * w.y;
    float t2 = v.z * rs * w.z, t3 = v.w * rs * w.w;
    ushort4 b; b.x = f2bf(t0); b.y = f2bf(t1); b.z = f2bf(t2); b.w = f2bf(t3);
    ((ushort4*)(t_out + (size_t)t * H_DIM))[i] = b;
#pragma unroll
    for (int q = 0; q < 16; q++) {
      float4 g = ((const float4*)(gate_w + (size_t)q * H_DIM))[i];
      part[q] += t0 * g.x + t1 * g.y + t2 * g.z + t3 * g.w;
    }
  }
  __shared__ float lg[4][16];
#pragma unroll
  for (int q = 0; q < 16; q++) {
    float p = part[q];
#pragma unroll
    for (int o = 1; o < 64; o <<= 1) p += __shfl_xor(p, o, 64);
    if ((tid & 63) == 0) lg[tid >> 6][q] = p;
  }
  __syncthreads();
  if (tid == 0) {
    float logit[16];
    for (int q = 0; q < 16; q++)
      logit[q] = lg[0][q] + lg[1][q] + lg[2][q] + lg[3][q] + gate_b[q];
    unsigned used = 0; int idx[4]; float val[4];
    for (int k = 0; k < 4; k++) {
      float best = -3.4e38f; int bi = 0;
      for (int q = 0; q < 16; q++)
        if (!((used >> q) & 1u) && logit[q] > best) { best = logit[q]; bi = q; }
      used |= 1u << bi; idx[k] = bi; val[k] = best;
    }
    float s0 = 0.f, w4[4];
    for (int k = 0; k < 4; k++) { w4[k] = expf(val[k] - val[0]); s0 += w4[k]; }
    for (int k = 0; k < 4; k++) {
      topk_id[t * 4 + k] = idx[k];
      topk_w[t * 4 + k] = w4[k] / s0;
      atomicAdd(&counts[idx[k]], 1);
    }
  }
}

// ---------------- K2a: padded prefix offsets ----------------
__global__ void k_offsets(const int* __restrict__ counts, int* __restrict__ d_off) {
  if (threadIdx.x == 0) {
    int acc = 0;
    for (int q = 0; q < 16; q++) {
      d_off[q] = acc;
      acc += ((counts[q] + PADM - 1) / PADM) * PADM;
    }
    d_off[16] = acc;
  }
}

// ---------------- K2b: routing lists (token order); padding tok = -1 ----------------
__global__ __launch_bounds__(256) void k_fill(
    const int* __restrict__ topk_id, const float* __restrict__ topk_w,
    const int* __restrict__ counts, const int* __restrict__ d_off,
    int* __restrict__ perm_tok, float* __restrict__ perm_w,
    int* __restrict__ perm_sl)
{
  int e = blockIdx.x;
  int base = d_off[e], pe = d_off[e + 1] - base, cnt = counts[e];
  int tid = threadIdx.x, lane = tid & 63, wv = tid >> 6;
  __shared__ int wsum[4];
  int pos = 0;
  for (int c0 = 0; c0 < T_TOK; c0 += 256) {
    int tok = c0 + tid;
    int4 ids = ((const int4*)topk_id)[tok];
    int flag = 0, slot = 0;
    if (ids.x == e) { flag = 1; slot = 0; }
    else if (ids.y == e) { flag = 1; slot = 1; }
    else if (ids.z == e) { flag = 1; slot = 2; }
    else if (ids.w == e) { flag = 1; slot = 3; }
    unsigned long long b = __ballot(flag);
    int wprefix = __popcll(b & ((1ULL << lane) - 1ULL));
    if (lane == 0) wsum[wv] = __popcll(b);
    __syncthreads();
    int woff = 0;
    for (int i = 0; i < wv; i++) woff += wsum[i];
    int tot = wsum[0] + wsum[1] + wsum[2] + wsum[3];
    if (flag) {
      int p = base + pos + woff + wprefix;
      perm_tok[p] = tok;
      perm_w[p] = topk_w[tok * 4 + slot];
      perm_sl[p] = slot;
    }
    pos += tot;
    __syncthreads();
  }
  for (int i = cnt + tid; i < pe; i += 256) {
    perm_tok[base + i] = -1;
    perm_w[base + i] = 0.f;
    perm_sl[base + i] = 0;
  }
}

// ---- staging macros (512 threads; chunk tid + optional chunk 512+tid) ----
#define STAGE_A(abuf, ktn) do {                                               \
  gl_lds16(aptr0 + (size_t)(ktn) * BK, lds + (abuf) * ABUF + adst0);          \
  if (tid < 256)                                                              \
    gl_lds16(aptr1 + (size_t)(ktn) * BK, lds + (abuf) * ABUF + adst1);        \
} while (0)

#define LOAD_B(set, ktn) do {                                                 \
  set[0][0] = bptr0[(ktn) * 8]; set[0][1] = bptr0[(ktn) * 8 + 1];             \
  if (tid < 256) { set[1][0] = bptr1[(ktn) * 8]; set[1][1] = bptr1[(ktn) * 8 + 1]; } \
} while (0)

#define PACK_B(set, bbuf) do {                                                \
  uint4 p0;                                                                   \
  p0.x = cpk(set[0][0].x, set[0][0].y); p0.y = cpk(set[0][0].z, set[0][0].w); \
  p0.z = cpk(set[0][1].x, set[0][1].y); p0.w = cpk(set[0][1].z, set[0][1].w); \
  *(uint4*)(lds + BOFF + (bbuf) * BBUF + bdst0) = p0;                         \
  if (tid < 256) {                                                            \
    uint4 p1;                                                                 \
    p1.x = cpk(set[1][0].x, set[1][0].y); p1.y = cpk(set[1][0].z, set[1][0].w); \
    p1.z = cpk(set[1][1].x, set[1][1].y); p1.w = cpk(set[1][1].z, set[1][1].w); \
    *(uint4*)(lds + BOFF + (bbuf) * BBUF + bdst1) = p1;                       \
  }                                                                           \
} while (0)

// Pipeline (A and B both rotate buffers mod 3):
//  prologue: A(0),A(1) staged; B(0),B(1) loaded+packed; B(2) loaded into bvA.
//  step kt:  STAGE_A((kt+2)%3, kt+2); COMP(kt%3);
//            PACK(set with B(kt+2) -> buf (kt+2)%3)   [full-step-old load]
//            LOAD(other set, kt+3); lgkmcnt(0)+barrier.
//  In-order vmcnt: pack at kt drains through B(kt+2) (issued end of kt-1,
//  after STAGE_A(kt+1)) -> A(kt+1) landed. Tail uses vmcnt(0) (2 steps).
#define GEMM_PIPE(COMP) do {                                                  \
  STAGE_A(0, 0); STAGE_A(1, 1);                                               \
  LOAD_B(bvA, 0);                                                             \
  PACK_B(bvA, 0);                                                             \
  LOAD_B(bvB, 1);                                                             \
  PACK_B(bvB, 1);                                                             \
  LOAD_B(bvA, 2);                                                             \
  ENDSTEP();                                                                  \
  int ca = 0;                                                                 \
  _Pragma("unroll 1")                                                         \
  for (int u = 0; u < NK / 2; u++) {                                          \
    int kt = 2 * u;                                                           \
    int ca1 = ca + 1; if (ca1 >= 3) ca1 -= 3;                                 \
    int ca2 = ca + 2; if (ca2 >= 3) ca2 -= 3;                                 \
    if (kt + 2 < NK) STAGE_A(ca2, kt + 2);                                    \
    COMP(ca);                                                                 \
    __builtin_amdgcn_sched_barrier(0);                                        \
    if (kt + 2 < NK) PACK_B(bvA, ca2);                                        \
    else asm volatile("s_waitcnt vmcnt(0)" ::: "memory");                     \
    if (kt + 3 < NK) LOAD_B(bvB, kt + 3);                                     \
    ENDSTEP();                                                                \
    if (kt + 3 < NK) STAGE_A(ca, kt + 3);                                     \
    COMP(ca1);                                                                \
    __builtin_amdgcn_sched_barrier(0);                                        \
    if (kt + 3 < NK) PACK_B(bvB, ca);                                         \
    else asm volatile("s_waitcnt vmcnt(0)" ::: "memory");                     \
    if (kt + 4 < NK) LOAD_B(bvA, kt + 4);                                     \
    ENDSTEP();                                                                \
    ca = ca2;                                                                 \
  }                                                                           \
} while (0)

// gemm1 compute: 3 A-frags x (3 gate + 3 lin) = 18 MFMA / wave-step
#define COMP1(cb) do {                                                        \
  const unsigned char* Ab = lds + (cb) * ABUF;                                \
  const unsigned char* Bb = lds + BOFF + (cb) * BBUF;                         \
  short8 a0 = *(const short8*)(Ab + abase);                                   \
  short8 a1 = *(const short8*)(Ab + abase + 1024);                            \
  short8 a2 = *(const short8*)(Ab + abase + 2048);                            \
  __builtin_amdgcn_s_setprio(1);                                              \
  _Pragma("unroll")                                                           \
  for (int n = 0; n < 3; n++) {                                               \
    short8 bg = *(const short8*)(Bb + bgbase + n * 1024);                     \
    short8 bl = *(const short8*)(Bb + blbase + n * 1024);                     \
    accg[0][n] = __builtin_amdgcn_mfma_f32_16x16x32_bf16(a0, bg, accg[0][n], 0, 0, 0); \
    accg[1][n] = __builtin_amdgcn_mfma_f32_16x16x32_bf16(a1, bg, accg[1][n], 0, 0, 0); \
    accg[2][n] = __builtin_amdgcn_mfma_f32_16x16x32_bf16(a2, bg, accg[2][n], 0, 0, 0); \
    accl[0][n] = __builtin_amdgcn_mfma_f32_16x16x32_bf16(a0, bl, accl[0][n], 0, 0, 0); \
    accl[1][n] = __builtin_amdgcn_mfma_f32_16x16x32_bf16(a1, bl, accl[1][n], 0, 0, 0); \
    accl[2][n] = __builtin_amdgcn_mfma_f32_16x16x32_bf16(a2, bl, accl[2][n], 0, 0, 0); \
  }                                                                           \
  __builtin_amdgcn_s_setprio(0);                                              \
} while (0)

// gemm2 compute: 3 A-frags x 6 B-frags = 18 MFMA / wave-step
#define COMP2(cb) do {                                                        \
  const unsigned char* Ab = lds + (cb) * ABUF;                                \
  const unsigned char* Bb = lds + BOFF + (cb) * BBUF;                         \
  short8 a0 = *(const short8*)(Ab + abase);                                   \
  short8 a1 = *(const short8*)(Ab + abase + 1024);                            \
  short8 a2 = *(const short8*)(Ab + abase + 2048);                            \
  __builtin_amdgcn_s_setprio(1);                                              \
  _Pragma("unroll")                                                           \
  for (int n = 0; n < 6; n++) {                                               \
    short8 b = *(const short8*)(Bb + bbase + n * 1024);                       \
    acc[0][n] = __builtin_amdgcn_mfma_f32_16x16x32_bf16(a0, b, acc[0][n], 0, 0, 0); \
    acc[1][n] = __builtin_amdgcn_mfma_f32_16x16x32_bf16(a1, b, acc[1][n], 0, 0, 0); \
    acc[2][n] = __builtin_amdgcn_mfma_f32_16x16x32_bf16(a2, b, acc[2][n], 0, 0, 0); \
  }                                                                           \
  __builtin_amdgcn_s_setprio(0);                                              \
} while (0)

// ================= K3: grouped gemm1 + bias + SwiGLU -> act =================
__global__ __launch_bounds__(512, 2) void k_gemm1(
    const unsigned short* __restrict__ t_bf16,
    const float* __restrict__ w1, const float* __restrict__ b1,
    const int* __restrict__ perm_tok, const int* __restrict__ d_off,
    unsigned short* __restrict__ act)
{
  __shared__ __align__(16) unsigned char lds[3 * ABUF + 3 * BBUF];  // 72 KB
  const int total = d_off[16];
  int bid = blockIdx.x;
  int wg = (bid & 7) * (G1 / 8) + (bid >> 3);   // XCD-chunked, rt fastest
  int ct = wg / MAX_RT, rt = wg % MAX_RT;
  int rowbase = rt * PADM;
  if (rowbase >= total) return;
  int e = 0;
#pragma unroll
  for (int q = 0; q < E_NUM; q++) if (d_off[q + 1] <= rowbase) e = q + 1;

  int tid = threadIdx.x, lane = tid & 63, wv = tid >> 6;
  int wm = wv & 3, wn = wv >> 2;
  int lr = lane & 15, ch = lane >> 4;
  unsigned swz16 = (unsigned)((ch ^ ((lr >> 1) & 3)) << 4);
  unsigned abase  = (unsigned)((wm * 48 + lr) * 64) + swz16;   // +mf*1024
  unsigned bgbase = (unsigned)((wn * 48 + lr) * 64) + swz16;   // +nf*1024
  unsigned blbase = bgbase + 6144;                             // lin rows +96

  const unsigned short* aptr0; const unsigned short* aptr1 = 0;
  unsigned adst0, adst1 = 0;
  {
    int cl = tid, r = cl >> 2, c = cl & 3;
    int tok = perm_tok[rowbase + r]; if (tok < 0) tok = 0;
    aptr0 = t_bf16 + (size_t)tok * H_DIM + ((c ^ ((r >> 1) & 3)) * 8);
    adst0 = (unsigned)cl * 16;
  }
  if (tid < 256) {
    int cl = 512 + tid, r = cl >> 2, c = cl & 3;
    int tok = perm_tok[rowbase + r]; if (tok < 0) tok = 0;
    aptr1 = t_bf16 + (size_t)tok * H_DIM + ((c ^ ((r >> 1) & 3)) * 8);
    adst1 = (unsigned)cl * 16;
  }
  const float4* bptr0; const float4* bptr1 = 0;
  unsigned bdst0, bdst1 = 0;
  {
    int cl = tid, rr = cl >> 2, c = cl & 3;
    size_t grow = (size_t)e * (2 * H_DIM) +
                  (rr < 96 ? (size_t)(ct * 96 + rr) : (size_t)(H_DIM + ct * 96 + (rr - 96)));
    bptr0 = (const float4*)(w1 + grow * H_DIM) + c * 2;
    bdst0 = (unsigned)(rr * 64 + ((c ^ ((rr >> 1) & 3)) << 4));
  }
  if (tid < 256) {
    int cl = 512 + tid, rr = cl >> 2, c = cl & 3;
    size_t grow = (size_t)(H_DIM + ct * 96 + (rr - 96)) + (size_t)e * (2 * H_DIM);
    bptr1 = (const float4*)(w1 + grow * H_DIM) + c * 2;
    bdst1 = (unsigned)(rr * 64 + ((c ^ ((rr >> 1) & 3)) << 4));
  }

  f32x4 zero = {0.f, 0.f, 0.f, 0.f};
  f32x4 accg[3][3], accl[3][3];
#pragma unroll
  for (int m = 0; m < 3; m++)
#pragma unroll
    for (int n = 0; n < 3; n++) { accg[m][n] = zero; accl[m][n] = zero; }
  float4 bvA[2][2], bvB[2][2];

  GEMM_PIPE(COMP1);

  int rq = lane >> 4;
#pragma unroll
  for (int m = 0; m < 3; m++) {
    int row0 = rowbase + wm * 48 + m * 16 + rq * 4;
#pragma unroll
    for (int n = 0; n < 3; n++) {
      int col = ct * 96 + wn * 48 + n * 16 + lr;
      float bg = b1[(size_t)e * (2 * H_DIM) + col];
      float bl = b1[(size_t)e * (2 * H_DIM) + H_DIM + col];
#pragma unroll
      for (int j = 0; j < 4; j++) {
        float g = accg[m][n][j] + bg;
        float l = accl[m][n][j] + bl;
        float s = 1.f / (1.f + __expf(-ALPHA * g));
        act[(size_t)(row0 + j) * H_DIM + col] = f2bf(g * s * (l + 1.f));
      }
    }
  }
}

// ========== K4: grouped gemm2 + bias; weighted bf16 slot stores ==========
__global__ __launch_bounds__(512, 2) void k_gemm2(
    const unsigned short* __restrict__ act,
    const float* __restrict__ w2, const float* __restrict__ b2,
    const int* __restrict__ perm_tok, const float* __restrict__ perm_w,
    const int* __restrict__ perm_sl, const int* __restrict__ d_off,
    unsigned short* __restrict__ yslot)
{
  __shared__ __align__(16) unsigned char lds[3 * ABUF + 3 * BBUF];  // 72 KB
  __shared__ int stok[PADM]; __shared__ float swt[PADM]; __shared__ int ssl[PADM];
  const int total = d_off[16];
  int bid = blockIdx.x;
  int wg = (bid & 7) * (G2 / 8) + (bid >> 3);
  int ct = wg / MAX_RT, rt = wg % MAX_RT;
  int rowbase = rt * PADM;
  if (rowbase >= total) return;
  int e = 0;
#pragma unroll
  for (int q = 0; q < E_NUM; q++) if (d_off[q + 1] <= rowbase) e = q + 1;

  int tid = threadIdx.x, lane = tid & 63, wv = tid >> 6;
  int wm = wv & 3, wn = wv >> 2;
  int lr = lane & 15, ch = lane >> 4;
  unsigned swz16 = (unsigned)((ch ^ ((lr >> 1) & 3)) << 4);
  unsigned abase = (unsigned)((wm * 48 + lr) * 64) + swz16;
  unsigned bbase = (unsigned)((wn * 96 + lr) * 64) + swz16;

  if (tid < PADM) {
    stok[tid] = perm_tok[rowbase + tid];
    swt[tid] = perm_w[rowbase + tid];
    ssl[tid] = perm_sl[rowbase + tid];
  }

  const unsigned short* aptr0; const unsigned short* aptr1 = 0;
  unsigned adst0, adst1 = 0;
  {
    int cl = tid, r = cl >> 2, c = cl & 3;
    aptr0 = act + (size_t)(rowbase + r) * H_DIM + ((c ^ ((r >> 1) & 3)) * 8);
    adst0 = (unsigned)cl * 16;
  }
  if (tid < 256) {
    int cl = 512 + tid, r = cl >> 2, c = cl & 3;
    aptr1 = act + (size_t)(rowbase + r) * H_DIM + ((c ^ ((r >> 1) & 3)) * 8);
    adst1 = (unsigned)cl * 16;
  }
  const float4* bptr0; const float4* bptr1 = 0;
  unsigned bdst0, bdst1 = 0;
  {
    int cl = tid, rr = cl >> 2, c = cl & 3;
    size_t grow = (size_t)e * H_DIM + (size_t)(ct * 192 + rr);
    bptr0 = (const float4*)(w2 + grow * H_DIM) + c * 2;
    bdst0 = (unsigned)(rr * 64 + ((c ^ ((rr >> 1) & 3)) << 4));
  }
  if (tid < 256) {
    int cl = 512 + tid, rr = cl >> 2, c = cl & 3;
    size_t grow = (size_t)e * H_DIM + (size_t)(ct * 192 + rr);
    bptr1 = (const float4*)(w2 + grow * H_DIM) + c * 2;
    bdst1 = (unsigned)(rr * 64 + ((c ^ ((rr >> 1) & 3)) << 4));
  }

  f32x4 zero = {0.f, 0.f, 0.f, 0.f};
  f32x4 acc[3][6];
#pragma unroll
  for (int m = 0; m < 3; m++)
#pragma unroll
    for (int n = 0; n < 6; n++) acc[m][n] = zero;
  float4 bvA[2][2], bvB[2][2];

  GEMM_PIPE(COMP2);

  int rq = lane >> 4;
#pragma unroll
  for (int m = 0; m < 3; m++) {
    int rl0 = wm * 48 + m * 16 + rq * 4;
#pragma unroll
    for (int n = 0; n < 6; n++) {
      int col = ct * 192 + wn * 96 + n * 16 + lr;
      float b2v = b2[(size_t)e * H_DIM + col];
#pragma unroll
      for (int j = 0; j < 4; j++) {
        int rl = rl0 + j;
        int tk = stok[rl];
        if (tk >= 0) {
          float y = (acc[m][n][j] + b2v) * swt[rl];
          yslot[((size_t)ssl[rl] * T_TOK + tk) * H_DIM + col] = f2bf(y);
        }
      }
    }
  }
}

// ---------------- K5: combine — out = x + sum_k slot_k ----------------
__global__ __launch_bounds__(256) void k_comb(
    const float* __restrict__ x, const unsigned short* __restrict__ yslot,
    float* __restrict__ out)
{
  const int n8 = T_TOK * H_DIM / 8;
  int i = blockIdx.x * 256 + threadIdx.x;
  int stride = gridDim.x * 256;
  for (; i < n8; i += stride) {
    float4 x0 = ((const float4*)x)[2 * i];
    float4 x1 = ((const float4*)x)[2 * i + 1];
    float s[8] = {x0.x, x0.y, x0.z, x0.w, x1.x, x1.y, x1.z, x1.w};
#pragma unroll
    for (int k = 0; k < 4; k++) {
      uint4 v = ((const uint4*)(yslot + (size_t)k * T_TOK * H_DIM))[i];
      unsigned u[4] = {v.x, v.y, v.z, v.w};
#pragma unroll
      for (int q = 0; q < 4; q++) {
        s[2 * q]     += __uint_as_float(u[q] << 16);
        s[2 * q + 1] += __uint_as_float(u[q] & 0xffff0000u);
      }
    }
    float4 o0 = {s[0], s[1], s[2], s[3]};
    float4 o1 = {s[4], s[5], s[6], s[7]};
    ((float4*)out)[2 * i] = o0;
    ((float4*)out)[2 * i + 1] = o1;
  }
}

// ---------------- launch ----------------
extern "C" void kernel_launch(void* const* d_in, const int* in_sizes, int n_in,
                              void* d_out, int out_size, void* d_ws, size_t ws_size,
                              hipStream_t stream)
{
  const float* x      = (const float*)d_in[0];
  const float* norm_w = (const float*)d_in[1];
  const float* gate_w = (const float*)d_in[2];
  const float* gate_b = (const float*)d_in[3];
  const float* w1     = (const float*)d_in[4];
  const float* b1     = (const float*)d_in[5];
  const float* w2     = (const float*)d_in[6];
  const float* b2     = (const float*)d_in[7];
  float* out = (float*)d_out;
  char* ws = (char*)d_ws;

  // ws layout (~233.4 MB; ws_size >= 271.6 MB verified in R7)
  unsigned short* t_bf16  = (unsigned short*)(ws);                    // 23,592,960
  unsigned short* act     = (unsigned short*)(ws + 23592960);         // 115,015,680
  int*            topk_id = (int*)(ws + 138608640);
  float*          topk_w  = (float*)(ws + 138674176);
  int*            perm_tk = (int*)(ws + 138739712);
  float*          perm_w  = (float*)(ws + 138819584);
  int*            perm_sl = (int*)(ws + 138899456);
  int*            counts  = (int*)(ws + 138979328);
  int*            d_off   = (int*)(ws + 138979392);
  unsigned short* yslot   = (unsigned short*)(ws + 138979840);        // 94,371,840

  hipMemsetAsync(counts, 0, 64, stream);
  hipLaunchKernelGGL(k_norm_gate, dim3(T_TOK), dim3(256), 0, stream,
                     x, norm_w, gate_w, gate_b, t_bf16, topk_id, topk_w, counts);
  hipLaunchKernelGGL(k_offsets, dim3(1), dim3(64), 0, stream, counts, d_off);
  hipLaunchKernelGGL(k_fill, dim3(16), dim3(256), 0, stream,
                     topk_id, topk_w, counts, d_off, perm_tk, perm_w, perm_sl);
  hipLaunchKernelGGL(k_gemm1, dim3(G1), dim3(512), 0, stream,
                     t_bf16, w1, b1, perm_tk, d_off, act);
  hipLaunchKernelGGL(k_gemm2, dim3(G2), dim3(512), 0, stream,
                     act, w2, b2, perm_tk, perm_w, perm_sl, d_off, yslot);
  hipLaunchKernelGGL(k_comb, dim3(2048), dim3(256), 0, stream, x, yslot, out);
}

// Round 12
// 1904.805 us; speedup vs baseline: 1.0019x; 1.0019x over previous
//
#include <hip/hip_runtime.h>
#include <hip/hip_bf16.h>
#include <math.h>
#include <stdint.h>

// Problem constants
#define T_TOK 4096
#define H_DIM 2880
#define E_NUM 16
#define ALPHA 1.702f
#define EPS_RMS 1e-5f

// ---- fallback (R10-proven) geometry ----
#define PADM_F 192
#define BK_F 32
#define NK_F (H_DIM / BK_F)     // 90
#define MAX_RT_F 104
#define G1F (MAX_RT_F * 30)     // 3120
#define G2F (MAX_RT_F * 15)     // 1560
#define ABUF_F 12288
#define BBUF_F 12288
#define BOFF_F 36864            // fallback LDS 60 KB

// ---- new 8-phase geometry (bf16 weights, all-gload_lds, counted vmcnt) ----
#define PADM_N 256
#define BK_N 64
#define NK_N (H_DIM / BK_N)     // 45
#define MAX_RT_N 80
#define G1N (MAX_RT_N * 30)     // 2400 (div 8)
#define G2N (MAX_RT_N * 15)     // 1200 (div 8)
#define TILE_N 57344            // A 32KB @0 + B 24KB @32768, x2 dbuf = 112KB

typedef __attribute__((ext_vector_type(8))) short short8;
typedef __attribute__((ext_vector_type(4))) float f32x4;

__device__ __forceinline__ unsigned short f2bf(float f) {
  unsigned u = __float_as_uint(f);
  return (unsigned short)((u + 0x7fffu + ((u >> 16) & 1u)) >> 16);
}
__device__ __forceinline__ unsigned cpk(float a, float b) {
  unsigned r;
  asm("v_cvt_pk_bf16_f32 %0, %1, %2" : "=v"(r) : "v"(a), "v"(b));
  return r;
}
__device__ __forceinline__ void gl_lds16(const void* g, unsigned char* lds_dst) {
  __builtin_amdgcn_global_load_lds(
      (const __attribute__((address_space(1))) void*)g,
      (__attribute__((address_space(3))) void*)lds_dst, 16, 0, 0);
}
#define WAITN(n) asm volatile("s_waitcnt vmcnt(" #n ")" ::: "memory")
#define ENDSTEP() do {                                           \
    asm volatile("s_waitcnt lgkmcnt(0)" ::: "memory");           \
    __builtin_amdgcn_s_barrier();                                \
    __builtin_amdgcn_sched_barrier(0);                           \
  } while (0)

// ---------------- K1: rmsnorm + fp32 gate + top4 ----------------
__global__ __launch_bounds__(256) void k_norm_gate(
    const float* __restrict__ x, const float* __restrict__ norm_w,
    const float* __restrict__ gate_w, const float* __restrict__ gate_b,
    unsigned short* __restrict__ t_out,
    int* __restrict__ topk_id, float* __restrict__ topk_w,
    int* __restrict__ counts)
{
  int t = blockIdx.x, tid = threadIdx.x;
  const float4* xr = (const float4*)(x + (size_t)t * H_DIM);
  float4 xa[3];
  float ss = 0.f;
  int j = 0;
  for (int i = tid; i < 720; i += 256, j++) {
    float4 v = xr[i]; xa[j] = v;
    ss += v.x * v.x + v.y * v.y + v.z * v.z + v.w * v.w;
  }
#pragma unroll
  for (int o = 1; o < 64; o <<= 1) ss += __shfl_xor(ss, o, 64);
  __shared__ float red[4];
  if ((tid & 63) == 0) red[tid >> 6] = ss;
  __syncthreads();
  float rs = rsqrtf((red[0] + red[1] + red[2] + red[3]) * (1.f / H_DIM) + EPS_RMS);

  float part[16];
#pragma unroll
  for (int q = 0; q < 16; q++) part[q] = 0.f;
  j = 0;
  for (int i = tid; i < 720; i += 256, j++) {
    float4 v = xa[j];
    float4 w = ((const float4*)norm_w)[i];
    float t0 = v.x * rs * w.x, t1 = v.y * rs * w.y;
    float t2 = v.z * rs * w.z, t3 = v.w * rs * w.w;
    ushort4 b; b.x = f2bf(t0); b.y = f2bf(t1); b.z = f2bf(t2); b.w = f2bf(t3);
    ((ushort4*)(t_out + (size_t)t * H_DIM))[i] = b;
#pragma unroll
    for (int q = 0; q < 16; q++) {
      float4 g = ((const float4*)(gate_w + (size_t)q * H_DIM))[i];
      part[q] += t0 * g.x + t1 * g.y + t2 * g.z + t3 * g.w;
    }
  }
  __shared__ float lg[4][16];
#pragma unroll
  for (int q = 0; q < 16; q++) {
    float p = part[q];
#pragma unroll
    for (int o = 1; o < 64; o <<= 1) p += __shfl_xor(p, o, 64);
    if ((tid & 63) == 0) lg[tid >> 6][q] = p;
  }
  __syncthreads();
  if (tid == 0) {
    float logit[16];
    for (int q = 0; q < 16; q++)
      logit[q] = lg[0][q] + lg[1][q] + lg[2][q] + lg[3][q] + gate_b[q];
    unsigned used = 0; int idx[4]; float val[4];
    for (int k = 0; k < 4; k++) {
      float best = -3.4e38f; int bi = 0;
      for (int q = 0; q < 16; q++)
        if (!((used >> q) & 1u) && logit[q] > best) { best = logit[q]; bi = q; }
      used |= 1u << bi; idx[k] = bi; val[k] = best;
    }
    float s0 = 0.f, w4[4];
    for (int k = 0; k < 4; k++) { w4[k] = expf(val[k] - val[0]); s0 += w4[k]; }
    for (int k = 0; k < 4; k++) {
      topk_id[t * 4 + k] = idx[k];
      topk_w[t * 4 + k] = w4[k] / s0;
      atomicAdd(&counts[idx[k]], 1);
    }
  }
}

// ---------------- K2a: padded prefix offsets (pad as arg) ----------------
__global__ void k_offsets(const int* __restrict__ counts, int* __restrict__ d_off, int pad) {
  if (threadIdx.x == 0) {
    int acc = 0;
    for (int q = 0; q < 16; q++) {
      d_off[q] = acc;
      acc += ((counts[q] + pad - 1) / pad) * pad;
    }
    d_off[16] = acc;
  }
}

// ---------------- K2b: routing lists (token order); padding tok = -1 ----------------
__global__ __launch_bounds__(256) void k_fill(
    const int* __restrict__ topk_id, const float* __restrict__ topk_w,
    const int* __restrict__ counts, const int* __restrict__ d_off,
    int* __restrict__ perm_tok, float* __restrict__ perm_w,
    int* __restrict__ perm_sl)
{
  int e = blockIdx.x;
  int base = d_off[e], pe = d_off[e + 1] - base, cnt = counts[e];
  int tid = threadIdx.x, lane = tid & 63, wv = tid >> 6;
  __shared__ int wsum[4];
  int pos = 0;
  for (int c0 = 0; c0 < T_TOK; c0 += 256) {
    int tok = c0 + tid;
    int4 ids = ((const int4*)topk_id)[tok];
    int flag = 0, slot = 0;
    if (ids.x == e) { flag = 1; slot = 0; }
    else if (ids.y == e) { flag = 1; slot = 1; }
    else if (ids.z == e) { flag = 1; slot = 2; }
    else if (ids.w == e) { flag = 1; slot = 3; }
    unsigned long long b = __ballot(flag);
    int wprefix = __popcll(b & ((1ULL << lane) - 1ULL));
    if (lane == 0) wsum[wv] = __popcll(b);
    __syncthreads();
    int woff = 0;
    for (int i = 0; i < wv; i++) woff += wsum[i];
    int tot = wsum[0] + wsum[1] + wsum[2] + wsum[3];
    if (flag) {
      int p = base + pos + woff + wprefix;
      perm_tok[p] = tok;
      perm_w[p] = topk_w[tok * 4 + slot];
      perm_sl[p] = slot;
    }
    pos += tot;
    __syncthreads();
  }
  for (int i = cnt + tid; i < pe; i += 256) {
    perm_tok[base + i] = -1;
    perm_w[base + i] = 0.f;
    perm_sl[base + i] = 0;
  }
}

// ---------------- weight fp32 -> bf16 (RNE via v_cvt_pk_bf16_f32) ----------------
__global__ __launch_bounds__(256) void k_cvt(
    const float* __restrict__ src, unsigned short* __restrict__ dst, int n8)
{
  int i = blockIdx.x * 256 + threadIdx.x;
  int stride = gridDim.x * 256;
  for (; i < n8; i += stride) {
    float4 a = ((const float4*)src)[2 * i];
    float4 b = ((const float4*)src)[2 * i + 1];
    uint4 o;
    o.x = cpk(a.x, a.y); o.y = cpk(a.z, a.w);
    o.z = cpk(b.x, b.y); o.w = cpk(b.z, b.w);
    ((uint4*)dst)[i] = o;
  }
}

// ================== NEW: 8-phase all-gload_lds GEMM core ==================
// 512 thr, 8 waves 4Mx2N; per wave 64 rows x 96 cols (4 m-frags x 6 n-frags).
// Per K-tile (BK=64): 4 phases (m-half x n-half), 12 MFMA each.
// Stage units (1 gl_lds/thread each): A0..A3 (64 rows each), B0..B2 (64 rows).
// Tile kt's phases stage tile kt+1 into buf nxt: ph1:{A0,B0} ph2:{A1,B1}
// ph3:{A2,B2} ph4:{A3}. Counted waits: ph1-end vmcnt(3), ph2-end vmcnt(4),
// ph4-end vmcnt(3) (tail: 1/0/none). NO vmcnt(0) in steady state.
#define STG_A(u, t1) gl_lds16(aptr[u] + (size_t)(t1) * BK_N, lds + nxt * TILE_N + adst[u])
#define STG_B(u, t1) gl_lds16(bptr[u] + (size_t)(t1) * BK_N, lds + nxt * TILE_N + bdst[u])

#define PH_N(MH, NH, STG, WT) do {                                            \
  const unsigned char* Ab_ = lds + cur * TILE_N;                              \
  const unsigned char* Bb_ = Ab_ + 32768;                                     \
  short8 a00 = *(const short8*)(Ab_ + aoff + (MH * 2) * 8192 + sw0);          \
  short8 a01 = *(const short8*)(Ab_ + aoff + (MH * 2) * 8192 + sw1);          \
  short8 a10 = *(const short8*)(Ab_ + aoff + (MH * 2 + 1) * 8192 + sw0);      \
  short8 a11 = *(const short8*)(Ab_ + aoff + (MH * 2 + 1) * 8192 + sw1);      \
  short8 b00 = *(const short8*)(Bb_ + boff + (NH * 3 + 0) * 4096 + sw0);      \
  short8 b01 = *(const short8*)(Bb_ + boff + (NH * 3 + 0) * 4096 + sw1);      \
  short8 b10 = *(const short8*)(Bb_ + boff + (NH * 3 + 1) * 4096 + sw0);      \
  short8 b11 = *(const short8*)(Bb_ + boff + (NH * 3 + 1) * 4096 + sw1);      \
  short8 b20 = *(const short8*)(Bb_ + boff + (NH * 3 + 2) * 4096 + sw0);      \
  short8 b21 = *(const short8*)(Bb_ + boff + (NH * 3 + 2) * 4096 + sw1);      \
  STG;                                                                        \
  __builtin_amdgcn_s_barrier();                                               \
  asm volatile("s_waitcnt lgkmcnt(0)" ::: "memory");                          \
  __builtin_amdgcn_sched_barrier(0);                                          \
  __builtin_amdgcn_s_setprio(1);                                              \
  acc[MH*2][NH*3+0]   = __builtin_amdgcn_mfma_f32_16x16x32_bf16(a00, b00, acc[MH*2][NH*3+0], 0, 0, 0);   \
  acc[MH*2][NH*3+1]   = __builtin_amdgcn_mfma_f32_16x16x32_bf16(a00, b10, acc[MH*2][NH*3+1], 0, 0, 0);   \
  acc[MH*2][NH*3+2]   = __builtin_amdgcn_mfma_f32_16x16x32_bf16(a00, b20, acc[MH*2][NH*3+2], 0, 0, 0);   \
  acc[MH*2+1][NH*3+0] = __builtin_amdgcn_mfma_f32_16x16x32_bf16(a10, b00, acc[MH*2+1][NH*3+0], 0, 0, 0); \
  acc[MH*2+1][NH*3+1] = __builtin_amdgcn_mfma_f32_16x16x32_bf16(a10, b10, acc[MH*2+1][NH*3+1], 0, 0, 0); \
  acc[MH*2+1][NH*3+2] = __builtin_amdgcn_mfma_f32_16x16x32_bf16(a10, b20, acc[MH*2+1][NH*3+2], 0, 0, 0); \
  acc[MH*2][NH*3+0]   = __builtin_amdgcn_mfma_f32_16x16x32_bf16(a01, b01, acc[MH*2][NH*3+0], 0, 0, 0);   \
  acc[MH*2][NH*3+1]   = __builtin_amdgcn_mfma_f32_16x16x32_bf16(a01, b11, acc[MH*2][NH*3+1], 0, 0, 0);   \
  acc[MH*2][NH*3+2]   = __builtin_amdgcn_mfma_f32_16x16x32_bf16(a01, b21, acc[MH*2][NH*3+2], 0, 0, 0);   \
  acc[MH*2+1][NH*3+0] = __builtin_amdgcn_mfma_f32_16x16x32_bf16(a11, b01, acc[MH*2+1][NH*3+0], 0, 0, 0); \
  acc[MH*2+1][NH*3+1] = __builtin_amdgcn_mfma_f32_16x16x32_bf16(a11, b11, acc[MH*2+1][NH*3+1], 0, 0, 0); \
  acc[MH*2+1][NH*3+2] = __builtin_amdgcn_mfma_f32_16x16x32_bf16(a11, b21, acc[MH*2+1][NH*3+2], 0, 0, 0); \
  __builtin_amdgcn_s_setprio(0);                                              \
  WT;                                                                         \
  __builtin_amdgcn_s_barrier();                                               \
  __builtin_amdgcn_sched_barrier(0);                                          \
} while (0)

#define GEMM_PIPE_N() do {                                                    \
  _Pragma("unroll")                                                           \
  for (int u = 0; u < 4; u++) gl_lds16(aptr[u], lds + adst[u]);               \
  _Pragma("unroll")                                                           \
  for (int u = 0; u < 3; u++) gl_lds16(bptr[u], lds + bdst[u]);               \
  WAITN(0);                                                                   \
  __builtin_amdgcn_s_barrier();                                               \
  __builtin_amdgcn_sched_barrier(0);                                          \
  _Pragma("unroll 1")                                                         \
  for (int kt = 0; kt < NK_N; kt++) {                                         \
    int cur = kt & 1, nxt = cur ^ 1;                                          \
    bool st = (kt + 1 < NK_N);                                                \
    PH_N(0, 0, { if (st) { STG_A(0, kt + 1); STG_B(0, kt + 1); } },           \
         { if (st) WAITN(3); else WAITN(1); });                               \
    PH_N(0, 1, { if (st) { STG_A(1, kt + 1); STG_B(1, kt + 1); } },           \
         { if (st) WAITN(4); else WAITN(0); });                               \
    PH_N(1, 0, { if (st) { STG_A(2, kt + 1); STG_B(2, kt + 1); } }, );        \
    PH_N(1, 1, { if (st) { STG_A(3, kt + 1); } },                             \
         { if (st) WAITN(3); });                                              \
  }                                                                           \
} while (0)

// ---- K3n: grouped gemm1, 8-phase, bf16 weights ----
__global__ __launch_bounds__(512, 2) void k_gemm1_n(
    const unsigned short* __restrict__ t_bf16,
    const unsigned short* __restrict__ w1b, const float* __restrict__ b1,
    const int* __restrict__ perm_tok, const int* __restrict__ d_off,
    unsigned short* __restrict__ act)
{
  __shared__ __align__(16) unsigned char lds[2 * TILE_N];   // 112 KB
  const int total = d_off[16];
  int bid = blockIdx.x;
  int wg = (bid & 7) * (G1N / 8) + (bid >> 3);   // XCD-chunked, rt fastest
  int ct = wg / MAX_RT_N, rt = wg % MAX_RT_N;
  int rowbase = rt * PADM_N;
  if (rowbase >= total) return;
  int e = 0;
#pragma unroll
  for (int q = 0; q < E_NUM; q++) if (d_off[q + 1] <= rowbase) e = q + 1;

  int tid = threadIdx.x, lane = tid & 63, wv = tid >> 6;
  int wm = wv & 3, wn = wv >> 2;
  int lr = lane & 15, lh = lane >> 4;
  unsigned sw0 = (unsigned)((lh ^ (lr & 7)) << 4);
  unsigned sw1 = (unsigned)(((4 + lh) ^ (lr & 7)) << 4);
  unsigned aoff = (unsigned)((wm * 16 + lr) * 128);
  unsigned boff = (unsigned)((wn * 16 + lr) * 128);

  const unsigned short* aptr[4]; unsigned adst[4];
#pragma unroll
  for (int u = 0; u < 4; u++) {
    int cl = u * 512 + tid;
    int r = cl >> 3, c = cl & 7;
    int tok = perm_tok[rowbase + r]; if (tok < 0) tok = 0;
    aptr[u] = t_bf16 + (size_t)tok * H_DIM + ((c ^ (r & 7)) * 8);
    adst[u] = (unsigned)cl * 16;
  }
  const unsigned short* bptr[3]; unsigned bdst[3];
#pragma unroll
  for (int u = 0; u < 3; u++) {
    int cl = u * 512 + tid;
    int rb = cl >> 3, c = cl & 7;
    size_t wrow = (size_t)e * (2 * H_DIM) +
                  (rb < 96 ? (size_t)(ct * 96 + rb) : (size_t)(H_DIM + ct * 96 + (rb - 96)));
    bptr[u] = w1b + wrow * H_DIM + ((c ^ (rb & 7)) * 8);
    bdst[u] = 32768u + (unsigned)cl * 16;
  }

  f32x4 zero = {0.f, 0.f, 0.f, 0.f};
  f32x4 acc[4][6];
#pragma unroll
  for (int m = 0; m < 4; m++)
#pragma unroll
    for (int n = 0; n < 6; n++) acc[m][n] = zero;

  GEMM_PIPE_N();

  // epilogue: bias + SwiGLU (nf 0-2 gate pair with nf+3 lin, same col)
#pragma unroll
  for (int mf = 0; mf < 4; mf++) {
    int row0 = rowbase + mf * 64 + wm * 16 + lh * 4;
#pragma unroll
    for (int nf = 0; nf < 3; nf++) {
      int col = ct * 96 + nf * 32 + wn * 16 + lr;
      float bg = b1[(size_t)e * (2 * H_DIM) + col];
      float bl = b1[(size_t)e * (2 * H_DIM) + H_DIM + col];
#pragma unroll
      for (int j = 0; j < 4; j++) {
        float g = acc[mf][nf][j] + bg;
        float l = acc[mf][nf + 3][j] + bl;
        float s = 1.f / (1.f + __expf(-ALPHA * g));
        act[(size_t)(row0 + j) * H_DIM + col] = f2bf(g * s * (l + 1.f));
      }
    }
  }
}

// ---- K4n: grouped gemm2, 8-phase, bf16 weights; weighted bf16 slot stores ----
__global__ __launch_bounds__(512, 2) void k_gemm2_n(
    const unsigned short* __restrict__ act,
    const unsigned short* __restrict__ w2b, const float* __restrict__ b2,
    const int* __restrict__ perm_tok, const float* __restrict__ perm_w,
    const int* __restrict__ perm_sl, const int* __restrict__ d_off,
    unsigned short* __restrict__ yslot)
{
  __shared__ __align__(16) unsigned char lds[2 * TILE_N];   // 112 KB
  __shared__ int stok[PADM_N]; __shared__ float swt[PADM_N]; __shared__ int ssl[PADM_N];
  const int total = d_off[16];
  int bid = blockIdx.x;
  int wg = (bid & 7) * (G2N / 8) + (bid >> 3);
  int ct = wg / MAX_RT_N, rt = wg % MAX_RT_N;
  int rowbase = rt * PADM_N;
  if (rowbase >= total) return;
  int e = 0;
#pragma unroll
  for (int q = 0; q < E_NUM; q++) if (d_off[q + 1] <= rowbase) e = q + 1;

  int tid = threadIdx.x, lane = tid & 63, wv = tid >> 6;
  int wm = wv & 3, wn = wv >> 2;
  int lr = lane & 15, lh = lane >> 4;
  unsigned sw0 = (unsigned)((lh ^ (lr & 7)) << 4);
  unsigned sw1 = (unsigned)(((4 + lh) ^ (lr & 7)) << 4);
  unsigned aoff = (unsigned)((wm * 16 + lr) * 128);
  unsigned boff = (unsigned)((wn * 16 + lr) * 128);

  if (tid < PADM_N) {
    stok[tid] = perm_tok[rowbase + tid];
    swt[tid] = perm_w[rowbase + tid];
    ssl[tid] = perm_sl[rowbase + tid];
  }

  const unsigned short* aptr[4]; unsigned adst[4];
#pragma unroll
  for (int u = 0; u < 4; u++) {
    int cl = u * 512 + tid;
    int r = cl >> 3, c = cl & 7;
    aptr[u] = act + (size_t)(rowbase + r) * H_DIM + ((c ^ (r & 7)) * 8);
    adst[u] = (unsigned)cl * 16;
  }
  const unsigned short* bptr[3]; unsigned bdst[3];
#pragma unroll
  for (int u = 0; u < 3; u++) {
    int cl = u * 512 + tid;
    int rb = cl >> 3, c = cl & 7;
    bptr[u] = w2b + ((size_t)e * H_DIM + (size_t)(ct * 192 + rb)) * H_DIM + ((c ^ (rb & 7)) * 8);
    bdst[u] = 32768u + (unsigned)cl * 16;
  }

  f32x4 zero = {0.f, 0.f, 0.f, 0.f};
  f32x4 acc[4][6];
#pragma unroll
  for (int m = 0; m < 4; m++)
#pragma unroll
    for (int n = 0; n < 6; n++) acc[m][n] = zero;

  GEMM_PIPE_N();

#pragma unroll
  for (int mf = 0; mf < 4; mf++) {
    int rl0 = mf * 64 + wm * 16 + lh * 4;
#pragma unroll
    for (int nf = 0; nf < 6; nf++) {
      int col = ct * 192 + nf * 32 + wn * 16 + lr;
      float b2v = b2[(size_t)e * H_DIM + col];
#pragma unroll
      for (int j = 0; j < 4; j++) {
        int rl = rl0 + j;
        int tk = stok[rl];
        if (tk >= 0) {
          float y = (acc[mf][nf][j] + b2v) * swt[rl];
          yslot[((size_t)ssl[rl] * T_TOK + tk) * H_DIM + col] = f2bf(y);
        }
      }
    }
  }
}

// ================== FALLBACK (R10-proven) GEMMs ==================
#define SA_F(abuf, ktn) do {                                                  \
  gl_lds16(aptr0 + (size_t)(ktn) * BK_F, lds + (abuf) * ABUF_F + adst0);      \
  if (tid < 256)                                                              \
    gl_lds16(aptr1 + (size_t)(ktn) * BK_F, lds + (abuf) * ABUF_F + adst1);    \
} while (0)
#define LB_F(ktn) do {                                                        \
  bv[0][0] = bptr0[(ktn) * 8]; bv[0][1] = bptr0[(ktn) * 8 + 1];               \
  if (tid < 256) { bv[1][0] = bptr1[(ktn) * 8]; bv[1][1] = bptr1[(ktn) * 8 + 1]; } \
} while (0)
#define PB_F(bbuf) do {                                                       \
  uint4 p0;                                                                   \
  p0.x = cpk(bv[0][0].x, bv[0][0].y); p0.y = cpk(bv[0][0].z, bv[0][0].w);     \
  p0.z = cpk(bv[0][1].x, bv[0][1].y); p0.w = cpk(bv[0][1].z, bv[0][1].w);     \
  *(uint4*)(lds + BOFF_F + (bbuf) * BBUF_F + bdst0) = p0;                     \
  if (tid < 256) {                                                            \
    uint4 p1;                                                                 \
    p1.x = cpk(bv[1][0].x, bv[1][0].y); p1.y = cpk(bv[1][0].z, bv[1][0].w);   \
    p1.z = cpk(bv[1][1].x, bv[1][1].y); p1.w = cpk(bv[1][1].z, bv[1][1].w);   \
    *(uint4*)(lds + BOFF_F + (bbuf) * BBUF_F + bdst1) = p1;                   \
  }                                                                           \
} while (0)
#define PIPE_F(COMP) do {                                                     \
  SA_F(0, 0); SA_F(1, 1); LB_F(0);                                            \
  PB_F(0);                                                                    \
  ENDSTEP();                                                                  \
  int ca = 0;                                                                 \
  _Pragma("unroll 1")                                                         \
  for (int u = 0; u < NK_F / 2; u++) {                                        \
    int kt = 2 * u;                                                           \
    int ca1 = ca + 1; if (ca1 >= 3) ca1 -= 3;                                 \
    int ca2 = ca + 2; if (ca2 >= 3) ca2 -= 3;                                 \
    if (kt + 1 < NK_F) LB_F(kt + 1);                                          \
    if (kt + 2 < NK_F) SA_F(ca2, kt + 2);                                     \
    COMP(ca, 0);                                                              \
    if (kt + 1 < NK_F) PB_F(1);                                               \
    ENDSTEP();                                                                \
    if (kt + 2 < NK_F) LB_F(kt + 2);                                          \
    if (kt + 3 < NK_F) SA_F(ca, kt + 3);                                      \
    COMP(ca1, 1);                                                             \
    if (kt + 2 < NK_F) PB_F(0);                                               \
    ENDSTEP();                                                                \
    ca = ca2;                                                                 \
  }                                                                           \
} while (0)
#define COMP1_F(ab, bb) do {                                                  \
  const unsigned char* Ab = lds + (ab) * ABUF_F;                              \
  const unsigned char* Bb = lds + BOFF_F + (bb) * BBUF_F;                     \
  short8 a0 = *(const short8*)(Ab + abase);                                   \
  short8 a1 = *(const short8*)(Ab + abase + 1024);                            \
  short8 a2 = *(const short8*)(Ab + abase + 2048);                            \
  __builtin_amdgcn_s_setprio(1);                                              \
  _Pragma("unroll")                                                           \
  for (int n = 0; n < 3; n++) {                                               \
    short8 bg = *(const short8*)(Bb + bgbase + n * 1024);                     \
    short8 bl = *(const short8*)(Bb + blbase + n * 1024);                     \
    accg[0][n] = __builtin_amdgcn_mfma_f32_16x16x32_bf16(a0, bg, accg[0][n], 0, 0, 0); \
    accg[1][n] = __builtin_amdgcn_mfma_f32_16x16x32_bf16(a1, bg, accg[1][n], 0, 0, 0); \
    accg[2][n] = __builtin_amdgcn_mfma_f32_16x16x32_bf16(a2, bg, accg[2][n], 0, 0, 0); \
    accl[0][n] = __builtin_amdgcn_mfma_f32_16x16x32_bf16(a0, bl, accl[0][n], 0, 0, 0); \
    accl[1][n] = __builtin_amdgcn_mfma_f32_16x16x32_bf16(a1, bl, accl[1][n], 0, 0, 0); \
    accl[2][n] = __builtin_amdgcn_mfma_f32_16x16x32_bf16(a2, bl, accl[2][n], 0, 0, 0); \
  }                                                                           \
  __builtin_amdgcn_s_setprio(0);                                              \
} while (0)
#define COMP2_F(ab, bb) do {                                                  \
  const unsigned char* Ab = lds + (ab) * ABUF_F;                              \
  const unsigned char* Bb = lds + BOFF_F + (bb) * BBUF_F;                     \
  short8 a0 = *(const short8*)(Ab + abase);                                   \
  short8 a1 = *(const short8*)(Ab + abase + 1024);                            \
  short8 a2 = *(const short8*)(Ab + abase + 2048);                            \
  __builtin_amdgcn_s_setprio(1);                                              \
  _Pragma("unroll")                                                           \
  for (int n = 0; n < 6; n++) {                                               \
    short8 b = *(const short8*)(Bb + bbase + n * 1024);                       \
    acc[0][n] = __builtin_amdgcn_mfma_f32_16x16x32_bf16(a0, b, acc[0][n], 0, 0, 0); \
    acc[1][n] = __builtin_amdgcn_mfma_f32_16x16x32_bf16(a1, b, acc[1][n], 0, 0, 0); \
    acc[2][n] = __builtin_amdgcn_mfma_f32_16x16x32_bf16(a2, b, acc[2][n], 0, 0, 0); \
  }                                                                           \
  __builtin_amdgcn_s_setprio(0);                                              \
} while (0)

__global__ __launch_bounds__(512, 4) void k_gemm1_f(
    const unsigned short* __restrict__ t_bf16,
    const float* __restrict__ w1, const float* __restrict__ b1,
    const int* __restrict__ perm_tok, const int* __restrict__ d_off,
    unsigned short* __restrict__ act)
{
  __shared__ __align__(16) unsigned char lds[3 * ABUF_F + 2 * BBUF_F];
  const int total = d_off[16];
  int bid = blockIdx.x;
  int wg = (bid & 7) * (G1F / 8) + (bid >> 3);
  int ct = wg / MAX_RT_F, rt = wg % MAX_RT_F;
  int rowbase = rt * PADM_F;
  if (rowbase >= total) return;
  int e = 0;
#pragma unroll
  for (int q = 0; q < E_NUM; q++) if (d_off[q + 1] <= rowbase) e = q + 1;

  int tid = threadIdx.x, lane = tid & 63, wv = tid >> 6;
  int wm = wv & 3, wn = wv >> 2;
  int lr = lane & 15, ch = lane >> 4;
  unsigned swz16 = (unsigned)((ch ^ ((lr >> 1) & 3)) << 4);
  unsigned abase  = (unsigned)((wm * 48 + lr) * 64) + swz16;
  unsigned bgbase = (unsigned)((wn * 48 + lr) * 64) + swz16;
  unsigned blbase = bgbase + 6144;

  const unsigned short* aptr0; const unsigned short* aptr1 = 0;
  unsigned adst0, adst1 = 0;
  {
    int cl = tid, r = cl >> 2, c = cl & 3;
    int tok = perm_tok[rowbase + r]; if (tok < 0) tok = 0;
    aptr0 = t_bf16 + (size_t)tok * H_DIM + ((c ^ ((r >> 1) & 3)) * 8);
    adst0 = (unsigned)cl * 16;
  }
  if (tid < 256) {
    int cl = 512 + tid, r = cl >> 2, c = cl & 3;
    int tok = perm_tok[rowbase + r]; if (tok < 0) tok = 0;
    aptr1 = t_bf16 + (size_t)tok * H_DIM + ((c ^ ((r >> 1) & 3)) * 8);
    adst1 = (unsigned)cl * 16;
  }
  const float4* bptr0; const float4* bptr1 = 0;
  unsigned bdst0, bdst1 = 0;
  {
    int cl = tid, rr = cl >> 2, c = cl & 3;
    size_t grow = (size_t)e * (2 * H_DIM) +
                  (rr < 96 ? (size_t)(ct * 96 + rr) : (size_t)(H_DIM + ct * 96 + (rr - 96)));
    bptr0 = (const float4*)(w1 + grow * H_DIM) + c * 2;
    bdst0 = (unsigned)(rr * 64 + ((c ^ ((rr >> 1) & 3)) << 4));
  }
  if (tid < 256) {
    int cl = 512 + tid, rr = cl >> 2, c = cl & 3;
    size_t grow = (size_t)(H_DIM + ct * 96 + (rr - 96)) + (size_t)e * (2 * H_DIM);
    bptr1 = (const float4*)(w1 + grow * H_DIM) + c * 2;
    bdst1 = (unsigned)(rr * 64 + ((c ^ ((rr >> 1) & 3)) << 4));
  }

  f32x4 zero = {0.f, 0.f, 0.f, 0.f};
  f32x4 accg[3][3], accl[3][3];
#pragma unroll
  for (int m = 0; m < 3; m++)
#pragma unroll
    for (int n = 0; n < 3; n++) { accg[m][n] = zero; accl[m][n] = zero; }
  float4 bv[2][2];

  PIPE_F(COMP1_F);

  int rq = lane >> 4;
#pragma unroll
  for (int m = 0; m < 3; m++) {
    int row0 = rowbase + wm * 48 + m * 16 + rq * 4;
#pragma unroll
    for (int n = 0; n < 3; n++) {
      int col = ct * 96 + wn * 48 + n * 16 + lr;
      float bg = b1[(size_t)e * (2 * H_DIM) + col];
      float bl = b1[(size_t)e * (2 * H_DIM) + H_DIM + col];
#pragma unroll
      for (int j = 0; j < 4; j++) {
        float g = accg[m][n][j] + bg;
        float l = accl[m][n][j] + bl;
        float s = 1.f / (1.f + __expf(-ALPHA * g));
        act[(size_t)(row0 + j) * H_DIM + col] = f2bf(g * s * (l + 1.f));
      }
    }
  }
}

__global__ __launch_bounds__(512, 4) void k_gemm2_f(
    const unsigned short* __restrict__ act,
    const float* __restrict__ w2, const float* __restrict__ b2,
    const int* __restrict__ perm_tok, const float* __restrict__ perm_w,
    const int* __restrict__ perm_sl, const int* __restrict__ d_off,
    unsigned short* __restrict__ yslot)
{
  __shared__ __align__(16) unsigned char lds[3 * ABUF_F + 2 * BBUF_F];
  __shared__ int stok[PADM_F]; __shared__ float swt[PADM_F]; __shared__ int ssl[PADM_F];
  const int total = d_off[16];
  int bid = blockIdx.x;
  int wg = (bid & 7) * (G2F / 8) + (bid >> 3);
  int ct = wg / MAX_RT_F, rt = wg % MAX_RT_F;
  int rowbase = rt * PADM_F;
  if (rowbase >= total) return;
  int e = 0;
#pragma unroll
  for (int q = 0; q < E_NUM; q++) if (d_off[q + 1] <= rowbase) e = q + 1;

  int tid = threadIdx.x, lane = tid & 63, wv = tid >> 6;
  int wm = wv & 3, wn = wv >> 2;
  int lr = lane & 15, ch = lane >> 4;
  unsigned swz16 = (unsigned)((ch ^ ((lr >> 1) & 3)) << 4);
  unsigned abase = (unsigned)((wm * 48 + lr) * 64) + swz16;
  unsigned bbase = (unsigned)((wn * 96 + lr) * 64) + swz16;

  if (tid < PADM_F) {
    stok[tid] = perm_tok[rowbase + tid];
    swt[tid] = perm_w[rowbase + tid];
    ssl[tid] = perm_sl[rowbase + tid];
  }

  const unsigned short* aptr0; const unsigned short* aptr1 = 0;
  unsigned adst0, adst1 = 0;
  {
    int cl = tid, r = cl >> 2, c = cl & 3;
    aptr0 = act + (size_t)(rowbase + r) * H_DIM + ((c ^ ((r >> 1) & 3)) * 8);
    adst0 = (unsigned)cl * 16;
  }
  if (tid < 256) {
    int cl = 512 + tid, r = cl >> 2, c = cl & 3;
    aptr1 = act + (size_t)(rowbase + r) * H_DIM + ((c ^ ((r >> 1) & 3)) * 8);
    adst1 = (unsigned)cl * 16;
  }
  const float4* bptr0; const float4* bptr1 = 0;
  unsigned bdst0, bdst1 = 0;
  {
    int cl = tid, rr = cl >> 2, c = cl & 3;
    size_t grow = (size_t)e * H_DIM + (size_t)(ct * 192 + rr);
    bptr0 = (const float4*)(w2 + grow * H_DIM) + c * 2;
    bdst0 = (unsigned)(rr * 64 + ((c ^ ((rr >> 1) & 3)) << 4));
  }
  if (tid < 256) {
    int cl = 512 + tid, rr = cl >> 2, c = cl & 3;
    size_t grow = (size_t)e * H_DIM + (size_t)(ct * 192 + rr);
    bptr1 = (const float4*)(w2 + grow * H_DIM) + c * 2;
    bdst1 = (unsigned)(rr * 64 + ((c ^ ((rr >> 1) & 3)) << 4));
  }

  f32x4 zero = {0.f, 0.f, 0.f, 0.f};
  f32x4 acc[3][6];
#pragma unroll
  for (int m = 0; m < 3; m++)
#pragma unroll
    for (int n = 0; n < 6; n++) acc[m][n] = zero;
  float4 bv[2][2];

  PIPE_F(COMP2_F);

  int rq = lane >> 4;
#pragma unroll
  for (int m = 0; m < 3; m++) {
    int rl0 = wm * 48 + m * 16 + rq * 4;
#pragma unroll
    for (int n = 0; n < 6; n++) {
      int col = ct * 192 + wn * 96 + n * 16 + lr;
      float b2v = b2[(size_t)e * H_DIM + col];
#pragma unroll
      for (int j = 0; j < 4; j++) {
        int rl = rl0 + j;
        int tk = stok[rl];
        if (tk >= 0) {
          float y = (acc[m][n][j] + b2v) * swt[rl];
          yslot[((size_t)ssl[rl] * T_TOK + tk) * H_DIM + col] = f2bf(y);
        }
      }
    }
  }
}

// ---------------- K5: combine — out = x + sum_k slot_k ----------------
__global__ __launch_bounds__(256) void k_comb(
    const float* __restrict__ x, const unsigned short* __restrict__ yslot,
    float* __restrict__ out)
{
  const int n8 = T_TOK * H_DIM / 8;
  int i = blockIdx.x * 256 + threadIdx.x;
  int stride = gridDim.x * 256;
  for (; i < n8; i += stride) {
    float4 x0 = ((const float4*)x)[2 * i];
    float4 x1 = ((const float4*)x)[2 * i + 1];
    float s[8] = {x0.x, x0.y, x0.z, x0.w, x1.x, x1.y, x1.z, x1.w};
#pragma unroll
    for (int k = 0; k < 4; k++) {
      uint4 v = ((const uint4*)(yslot + (size_t)k * T_TOK * H_DIM))[i];
      unsigned u[4] = {v.x, v.y, v.z, v.w};
#pragma unroll
      for (int q = 0; q < 4; q++) {
        s[2 * q]     += __uint_as_float(u[q] << 16);
        s[2 * q + 1] += __uint_as_float(u[q] & 0xffff0000u);
      }
    }
    float4 o0 = {s[0], s[1], s[2], s[3]};
    float4 o1 = {s[4], s[5], s[6], s[7]};
    ((float4*)out)[2 * i] = o0;
    ((float4*)out)[2 * i + 1] = o1;
  }
}

// ---------------- launch ----------------
extern "C" void kernel_launch(void* const* d_in, const int* in_sizes, int n_in,
                              void* d_out, int out_size, void* d_ws, size_t ws_size,
                              hipStream_t stream)
{
  const float* x      = (const float*)d_in[0];
  const float* norm_w = (const float*)d_in[1];
  const float* gate_w = (const float*)d_in[2];
  const float* gate_b = (const float*)d_in[3];
  const float* w1     = (const float*)d_in[4];
  const float* b1     = (const float*)d_in[5];
  const float* w2     = (const float*)d_in[6];
  const float* b2     = (const float*)d_in[7];
  float* out = (float*)d_out;
  char* ws = (char*)d_ws;

  // ws layout
  unsigned short* t_bf16  = (unsigned short*)(ws);                    // 23,592,960
  unsigned short* act     = (unsigned short*)(ws + 23592960);         // 117,964,800 (20480 rows)
  int*            topk_id = (int*)(ws + 141557760);                   // 65,536
  float*          topk_w  = (float*)(ws + 141623296);                 // 65,536
  int*            perm_tk = (int*)(ws + 141688832);                   // 81,920
  float*          perm_w  = (float*)(ws + 141770752);                 // 81,920
  int*            perm_sl = (int*)(ws + 141852672);                   // 81,920
  int*            counts  = (int*)(ws + 141934592);                   // 64
  int*            d_off   = (int*)(ws + 141934656);                   // 68
  unsigned short* yslot   = (unsigned short*)(ws + 141935104);        // 94,371,840
  unsigned short* wb      = (unsigned short*)(ws + 236306944);        // 530,841,600 (w1b; w2b overlays)
  const size_t NEED = 236306944ULL + 530841600ULL;                    // ~767.1 MB
  bool bigws = ws_size >= NEED;

  hipMemsetAsync(counts, 0, 64, stream);
  hipLaunchKernelGGL(k_norm_gate, dim3(T_TOK), dim3(256), 0, stream,
                     x, norm_w, gate_w, gate_b, t_bf16, topk_id, topk_w, counts);
  hipLaunchKernelGGL(k_offsets, dim3(1), dim3(64), 0, stream, counts, d_off,
                     bigws ? PADM_N : PADM_F);
  hipLaunchKernelGGL(k_fill, dim3(16), dim3(256), 0, stream,
                     topk_id, topk_w, counts, d_off, perm_tk, perm_w, perm_sl);
  if (bigws) {
    hipLaunchKernelGGL(k_cvt, dim3(2048), dim3(256), 0, stream, w1, wb, 33177600);
    hipLaunchKernelGGL(k_gemm1_n, dim3(G1N), dim3(512), 0, stream,
                       t_bf16, wb, b1, perm_tk, d_off, act);
    hipLaunchKernelGGL(k_cvt, dim3(2048), dim3(256), 0, stream, w2, wb, 16588800);
    hipLaunchKernelGGL(k_gemm2_n, dim3(G2N), dim3(512), 0, stream,
                       act, wb, b2, perm_tk, perm_w, perm_sl, d_off, yslot);
  } else {
    hipLaunchKernelGGL(k_gemm1_f, dim3(G1F), dim3(512), 0, stream,
                       t_bf16, w1, b1, perm_tk, d_off, act);
    hipLaunchKernelGGL(k_gemm2_f, dim3(G2F), dim3(512), 0, stream,
                       act, w2, b2, perm_tk, perm_w, perm_sl, d_off, yslot);
  }
  hipLaunchKernelGGL(k_comb, dim3(2048), dim3(256), 0, stream, x, yslot, out);
}